// Round 4
// baseline (368.545 us; speedup 1.0000x reference)
//
#include <hip/hip_runtime.h>

#define MAT_N 256
#define TPB   1024
#define ITERS 20

// One block per 256x256 matrix; 1024 threads = 32x32 grid of 8x8 register tiles.
// Multiplicative-domain Sinkhorn. KEY TRICK: the AMDGPU backend budgets VGPRs
// from computed max occupancy; with small LDS it targets 8 waves/EU = 64 VGPRs
// and spills E to scratch (R1-R3: 217-306us, spill-bound). We allocate >80KB of
// LDS so max occupancy is 1 block/CU (4 waves/EU) -> VGPR budget 128. Rows 0-5
// of each thread's 8x8 tile live in VGPRs (48 regs, total ~95 < 128, no spill);
// rows 6-7 live in a thread-private lane-interleaved LDS arena (espill[c][t],
// 16B lane stride -> conflict-free b128, no barriers: strictly thread-private).
// Row pass: in-wave shuffle butterfly. Col pass: shfl_xor(32) pair-reduce ->
// 16 swizzled LDS partial rows -> 2 barriers/iter.
__global__ __launch_bounds__(TPB) void sinkhorn_kernel(
    const float* __restrict__ x, float* __restrict__ out)
{
    const int t    = threadIdx.x;
    const int tR   = t >> 5;          // 0..31 tile row
    const int tC   = t & 31;          // 0..31 tile col
    const int row0 = tR << 3;
    const int col0 = tC << 3;
    const int w    = t >> 6;          // wave index 0..15
    const int rot  = (tC >> 2) & 7;   // bank-swizzle rotation for partial writes

    const float* __restrict__ xm = x   + (size_t)blockIdx.x * (MAT_N * MAT_N);
    float* __restrict__       om = out + (size_t)blockIdx.x * (MAT_N * MAT_N);

    __shared__ float4 espill[4][TPB];   // 64 KB: tile rows 6,7 (2 float4 each), thread-private
    __shared__ float  part[16][MAT_N];  // 16 KB: pair-reduced column partials, swizzled
    __shared__ float  gvec[MAT_N];      //  1 KB
    // total 81.25 KB > 80 KB -> 1 block/CU -> compiler VGPR budget = 128

    // ---- load tile, E = exp(x); rows 0..5 -> registers, rows 6..7 -> espill ----
    float E[6][8];
#pragma unroll
    for (int l = 0; l < 6; ++l) {
        const float* rp = xm + (row0 + l) * MAT_N + col0;
        float4 a = *(const float4*)(rp);
        float4 b = *(const float4*)(rp + 4);
        E[l][0] = __expf(a.x); E[l][1] = __expf(a.y);
        E[l][2] = __expf(a.z); E[l][3] = __expf(a.w);
        E[l][4] = __expf(b.x); E[l][5] = __expf(b.y);
        E[l][6] = __expf(b.z); E[l][7] = __expf(b.w);
    }
#pragma unroll
    for (int l = 6; l < 8; ++l) {
        const float* rp = xm + (row0 + l) * MAT_N + col0;
        float4 a = *(const float4*)(rp);
        float4 b = *(const float4*)(rp + 4);
        espill[(l - 6) * 2][t] =
            make_float4(__expf(a.x), __expf(a.y), __expf(a.z), __expf(a.w));
        espill[(l - 6) * 2 + 1][t] =
            make_float4(__expf(b.x), __expf(b.y), __expf(b.z), __expf(b.w));
    }

    float f[8], g[8];
#pragma unroll
    for (int l = 0; l < 8; ++l) f[l] = 1.0f;

    for (int it = 0; it < ITERS; ++it) {
        // ---------- column pass: g = 1 / (E^T f) ----------
        float p[8];
#pragma unroll
        for (int k = 0; k < 8; ++k) p[k] = E[0][k] * f[0];
#pragma unroll
        for (int l = 1; l < 6; ++l)
#pragma unroll
            for (int k = 0; k < 8; ++k) p[k] += E[l][k] * f[l];
        {   // LDS-resident rows 6,7
            float4 a = espill[0][t], b = espill[1][t];
            p[0] += a.x * f[6]; p[1] += a.y * f[6]; p[2] += a.z * f[6]; p[3] += a.w * f[6];
            p[4] += b.x * f[6]; p[5] += b.y * f[6]; p[6] += b.z * f[6]; p[7] += b.w * f[6];
            float4 c = espill[2][t], d = espill[3][t];
            p[0] += c.x * f[7]; p[1] += c.y * f[7]; p[2] += c.z * f[7]; p[3] += c.w * f[7];
            p[4] += d.x * f[7]; p[5] += d.y * f[7]; p[6] += d.z * f[7]; p[7] += d.w * f[7];
        }
        // combine the wave's two tile-rows (lane ^ 32 holds same columns, other row)
#pragma unroll
        for (int k = 0; k < 8; ++k) p[k] += __shfl_xor(p[k], 32, 64);
        if ((t & 32) == 0) {
            // swizzled write: 32 lanes -> 32 distinct banks
#pragma unroll
            for (int k = 0; k < 8; ++k)
                part[w][col0 + ((k + rot) & 7)] = p[k];
        }
        __syncthreads();
        if (t < MAT_N) {
            const int pos = (t & ~7) | (((t & 7) + (t >> 5)) & 7);  // swizzle inverse
            float s = 0.0f;
#pragma unroll
            for (int r = 0; r < 16; ++r) s += part[r][pos];
            gvec[t] = 1.0f / s;
        }
        __syncthreads();

        {
            float4 g0 = *(const float4*)&gvec[col0];
            float4 g1 = *(const float4*)&gvec[col0 + 4];
            g[0] = g0.x; g[1] = g0.y; g[2] = g0.z; g[3] = g0.w;
            g[4] = g1.x; g[5] = g1.y; g[6] = g1.z; g[7] = g1.w;
        }

        // ---------- row pass: f = 1 / (E g), all in-wave ----------
        float q[8];
#pragma unroll
        for (int l = 0; l < 6; ++l) {
            float s = E[l][0] * g[0];
#pragma unroll
            for (int k = 1; k < 8; ++k) s += E[l][k] * g[k];
            q[l] = s;
        }
        {   // LDS-resident rows 6,7
            float4 a = espill[0][t], b = espill[1][t];
            q[6] = a.x * g[0] + a.y * g[1] + a.z * g[2] + a.w * g[3]
                 + b.x * g[4] + b.y * g[5] + b.z * g[6] + b.w * g[7];
            float4 c = espill[2][t], d = espill[3][t];
            q[7] = c.x * g[0] + c.y * g[1] + c.z * g[2] + c.w * g[3]
                 + d.x * g[4] + d.y * g[5] + d.z * g[6] + d.w * g[7];
        }
        // butterfly over lane bits 0..4: each 32-lane half owns one tile-row band
#pragma unroll
        for (int m = 1; m <= 16; m <<= 1)
#pragma unroll
            for (int l = 0; l < 8; ++l) q[l] += __shfl_xor(q[l], m, 64);
#pragma unroll
        for (int l = 0; l < 8; ++l) f[l] = 1.0f / q[l];
    }

    // ---------- output: out = E * f[row] * g[col] ----------
#pragma unroll
    for (int l = 0; l < 6; ++l) {
        float fr = f[l];
        float* rp = om + (row0 + l) * MAT_N + col0;
        *(float4*)(rp)     = make_float4(E[l][0] * fr * g[0], E[l][1] * fr * g[1],
                                         E[l][2] * fr * g[2], E[l][3] * fr * g[3]);
        *(float4*)(rp + 4) = make_float4(E[l][4] * fr * g[4], E[l][5] * fr * g[5],
                                         E[l][6] * fr * g[6], E[l][7] * fr * g[7]);
    }
#pragma unroll
    for (int l = 6; l < 8; ++l) {
        float fr = f[l];
        float4 a = espill[(l - 6) * 2][t];
        float4 b = espill[(l - 6) * 2 + 1][t];
        float* rp = om + (row0 + l) * MAT_N + col0;
        *(float4*)(rp)     = make_float4(a.x * fr * g[0], a.y * fr * g[1],
                                         a.z * fr * g[2], a.w * fr * g[3]);
        *(float4*)(rp + 4) = make_float4(b.x * fr * g[4], b.y * fr * g[5],
                                         b.z * fr * g[6], b.w * fr * g[7]);
    }
}

extern "C" void kernel_launch(void* const* d_in, const int* in_sizes, int n_in,
                              void* d_out, int out_size, void* d_ws, size_t ws_size,
                              hipStream_t stream) {
    const float* x = (const float*)d_in[0];
    float* out = (float*)d_out;
    const int nmat = in_sizes[0] / (MAT_N * MAT_N);   // 512
    sinkhorn_kernel<<<nmat, TPB, 0, stream>>>(x, out);
}